// Round 4
// baseline (36247.205 us; speedup 1.0000x reference)
//
#include <hip/hip_runtime.h>
#include <hip/hip_bf16.h>

// Problem constants (fixed by harness inputs)
#define BATCH 128
#define NSAMP 4
#define BN    512        // BATCH*NSAMP
#define HID   512
#define EMBD  512
#define VOC   512
#define TLEN  100
#define MLEN  256
#define NGATE 2048       // 4*HID

// output flat offsets (FLOAT32 elements — reference outputs are f32/int32)
#define O_ZID     0L
#define O_ZSTATES 51200L
#define O_ZLP     26265600L
#define O_STEP    26266112L
#define O_ENT     26317312L
#define O_TOTAL   26317313L

// workspace offsets (floats) inside g_ws
#define OFF_H    0L         // [512][1024]
#define OFF_C    524288L    // [512][1024]
#define OFF_X    1048576L   // [512][512]
#define OFF_G    1310720L   // [512][2048]
#define OFF_Q    2359296L   // [512][512]
#define OFF_CTX  2621440L   // [512][512]
#define OFF_O2   2883584L   // [512][512]
#define OFF_LG   3145728L   // [512][512]
#define OFF_YR   3407872L   // [512][512]
#define OFF_BG   3670016L   // [2][2048]
#define OFF_ENT  3674112L   // [128]
#define OFF_SLP  3674240L   // [100*512]
#define WS_FLOATS 3725440L

__device__ float g_ws[WS_FLOATS];
__device__ int   g_ids[TLEN * BN];

// ---------------- threefry2x32 (JAX-exact, 20 rounds) ----------------
__device__ __forceinline__ unsigned rotl32(unsigned x, int r) {
  return (x << r) | (x >> (32 - r));
}
__device__ __forceinline__ void threefry2x32(unsigned k0, unsigned k1,
                                             unsigned& x0, unsigned& x1) {
  unsigned k2 = k0 ^ k1 ^ 0x1BD11BDAu;
#define TF_R(r) { x0 += x1; x1 = rotl32(x1, r); x1 ^= x0; }
  x0 += k0; x1 += k1;
  TF_R(13) TF_R(15) TF_R(26) TF_R(6)
  x0 += k1; x1 += k2 + 1u;
  TF_R(17) TF_R(29) TF_R(16) TF_R(24)
  x0 += k2; x1 += k0 + 2u;
  TF_R(13) TF_R(15) TF_R(26) TF_R(6)
  x0 += k0; x1 += k1 + 3u;
  TF_R(17) TF_R(29) TF_R(16) TF_R(24)
  x0 += k1; x1 += k2 + 4u;
  TF_R(13) TF_R(15) TF_R(26) TF_R(6)
  x0 += k2; x1 += k0 + 5u;
#undef TF_R
}

__device__ __forceinline__ float gumbel_from_bits(unsigned bits) {
  unsigned fb = (bits >> 9) | 0x3F800000u;
  float f = __uint_as_float(fb) - 1.0f;          // [0,1)
  const float TINY = 1.17549435e-38f;
  float u = fmaxf(f + TINY, TINY);               // == f unless f==0 (JAX-exact)
  return -logf(-logf(u));
}

// XLA-style logistic: 0.5 + 0.5*tanh(0.5*x)
__device__ __forceinline__ float sigf(float x) {
  return 0.5f + 0.5f * tanhf(0.5f * x);
}

// ---------------- fused two-segment fp32 GEMM ----------------
// C[m,n] = sum_k A1[m,k]*B1[n,k] (k<K1) + sum_k A2[m,k]*B2[n,k] (k<K2) + bias[n]
__global__ __launch_bounds__(256) void gemm2(
    long offA1, int lda1,
    const float* __restrict__ B1, int ldb1, int K1,
    long offA2, int lda2,
    const float* __restrict__ B2, int ldb2, int K2,
    const float* __restrict__ biasExt, long biasOff,
    long offC, int ldc)
{
  __shared__ float As[16][68];
  __shared__ float Bs[16][68];
  const int tid = threadIdx.x;
  const int tx  = tid & 15;        // n
  const int ty  = tid >> 4;        // m
  const int ldr = tid >> 2;        // 0..63 tile row for loading
  const int ldk = (tid & 3) << 2;  // 0,4,8,12
  const int m0 = blockIdx.y * 64;
  const int n0 = blockIdx.x * 64;
  float acc[4][4] = {{0.f}};

  for (int seg = 0; seg < 2; ++seg) {
    const float* A = g_ws + (seg ? offA2 : offA1);
    const float* B = seg ? B2 : B1;
    const int lda = seg ? lda2 : lda1;
    const int ldb = seg ? ldb2 : ldb1;
    const int K   = seg ? K2  : K1;
    for (int k0 = 0; k0 < K; k0 += 16) {
      float4 av = *(const float4*)(A + (size_t)(m0 + ldr) * lda + k0 + ldk);
      float4 bv = *(const float4*)(B + (size_t)(n0 + ldr) * ldb + k0 + ldk);
      __syncthreads();
      As[ldk + 0][ldr] = av.x; As[ldk + 1][ldr] = av.y;
      As[ldk + 2][ldr] = av.z; As[ldk + 3][ldr] = av.w;
      Bs[ldk + 0][ldr] = bv.x; Bs[ldk + 1][ldr] = bv.y;
      Bs[ldk + 2][ldr] = bv.z; Bs[ldk + 3][ldr] = bv.w;
      __syncthreads();
#pragma unroll
      for (int k = 0; k < 16; ++k) {
        float4 a = *(const float4*)&As[k][ty * 4];
        float4 b = *(const float4*)&Bs[k][tx * 4];
        acc[0][0] += a.x * b.x; acc[0][1] += a.x * b.y; acc[0][2] += a.x * b.z; acc[0][3] += a.x * b.w;
        acc[1][0] += a.y * b.x; acc[1][1] += a.y * b.y; acc[1][2] += a.y * b.z; acc[1][3] += a.y * b.w;
        acc[2][0] += a.z * b.x; acc[2][1] += a.z * b.y; acc[2][2] += a.z * b.z; acc[2][3] += a.z * b.w;
        acc[3][0] += a.w * b.x; acc[3][1] += a.w * b.y; acc[3][2] += a.w * b.z; acc[3][3] += a.w * b.w;
      }
    }
  }
  const float* bias = biasExt ? biasExt : (biasOff >= 0 ? g_ws + biasOff : nullptr);
  float* C = g_ws + offC;
#pragma unroll
  for (int i = 0; i < 4; ++i) {
    int row = m0 + ty * 4 + i;
    int col = n0 + tx * 4;
    float4 o;
    o.x = acc[i][0]; o.y = acc[i][1]; o.z = acc[i][2]; o.w = acc[i][3];
    if (bias) {
      o.x += bias[col]; o.y += bias[col + 1]; o.z += bias[col + 2]; o.w += bias[col + 3];
    }
    *(float4*)(C + (size_t)row * ldc + col) = o;
  }
}

// ---------------- LSTM cell elementwise (gate order i,f,g,o) ----------------
__global__ __launch_bounds__(256) void lstm_cell(long hoff, long coff)
{
  int idx = blockIdx.x * 256 + threadIdx.x;   // 0..262143
  int r = idx >> 9, j = idx & 511;
  const float* gr = g_ws + OFF_G + (size_t)r * NGATE;
  float* h = g_ws + hoff;
  float* c = g_ws + coff;
  float gi = gr[j], gf = gr[512 + j], gg = gr[1024 + j], go = gr[1536 + j];
  float cold = c[(size_t)r * 1024 + j];
  float cn = sigf(gf) * cold + sigf(gi) * tanhf(gg);
  float hn = sigf(go) * tanhf(cn);
  c[(size_t)r * 1024 + j] = cn;
  h[(size_t)r * 1024 + j] = hn;
}

// ---------------- attention: block b handles 4 samples sharing kv[b] ----------------
__global__ __launch_bounds__(256) void attn_kernel(
    const float* __restrict__ kv,          // [128][256][512]
    const void*  __restrict__ kvm_raw)     // [128][256] bool (u8/int32/f32 tolerated)
{
  __shared__ float qs[4][512];
  __shared__ float sc[4][256];
  const int b = blockIdx.x;
  const int tid = threadIdx.x;
  const int lane = tid & 63, wave = tid >> 6;
  const float* q   = g_ws + OFF_Q;
  float*       ctx = g_ws + OFF_CTX;
  const float* kvb = kv + (size_t)b * MLEN * HID;
  // dtype sniff: u8-bool storage of "true" row 0 gives word 0x01010101
  const unsigned* w32 = (const unsigned*)kvm_raw;
  const unsigned char* u8 = (const unsigned char*)kvm_raw;
  const bool u8mode = (w32[0] == 0x01010101u);
#pragma unroll
  for (int s = 0; s < 4; ++s) {
    qs[s][tid]       = q[(size_t)(b * 4 + s) * HID + tid];
    qs[s][tid + 256] = q[(size_t)(b * 4 + s) * HID + tid + 256];
  }
  __syncthreads();
  // pass 1: scores
  for (int m = wave; m < MLEN; m += 4) {
    const float* kr = kvb + (size_t)m * HID;
    float a0 = 0.f, a1 = 0.f, a2 = 0.f, a3 = 0.f;
    for (int d = lane; d < HID; d += 64) {
      float kvv = kr[d];
      a0 += qs[0][d] * kvv; a1 += qs[1][d] * kvv;
      a2 += qs[2][d] * kvv; a3 += qs[3][d] * kvv;
    }
#pragma unroll
    for (int off = 32; off > 0; off >>= 1) {
      a0 += __shfl_down(a0, off); a1 += __shfl_down(a1, off);
      a2 += __shfl_down(a2, off); a3 += __shfl_down(a3, off);
    }
    if (lane == 0) {
      bool on = u8mode ? (u8[b * MLEN + m] != 0) : (w32[b * MLEN + m] != 0u);
      float madd = on ? 0.0f : -1e9f;
      sc[0][m] = a0 + madd; sc[1][m] = a1 + madd;
      sc[2][m] = a2 + madd; sc[3][m] = a3 + madd;
    }
  }
  __syncthreads();
  // softmax (wave s handles sample s)
  {
    const int s = wave;
    float mx = -3.4e38f;
    for (int m = lane; m < MLEN; m += 64) mx = fmaxf(mx, sc[s][m]);
#pragma unroll
    for (int off = 32; off > 0; off >>= 1) mx = fmaxf(mx, __shfl_xor(mx, off));
    float sum = 0.f;
    for (int m = lane; m < MLEN; m += 64) {
      float e = expf(sc[s][m] - mx);
      sc[s][m] = e; sum += e;
    }
#pragma unroll
    for (int off = 32; off > 0; off >>= 1) sum += __shfl_xor(sum, off);
    for (int m = lane; m < MLEN; m += 64) sc[s][m] = sc[s][m] / sum;
  }
  __syncthreads();
  // pass 2: ctx
  float c00=0,c01=0,c10=0,c11=0,c20=0,c21=0,c30=0,c31=0;
  for (int m = 0; m < MLEN; ++m) {
    float k0v = kvb[(size_t)m * HID + tid];
    float k1v = kvb[(size_t)m * HID + tid + 256];
    float p0 = sc[0][m], p1 = sc[1][m], p2 = sc[2][m], p3 = sc[3][m];
    c00 += p0 * k0v; c01 += p0 * k1v;
    c10 += p1 * k0v; c11 += p1 * k1v;
    c20 += p2 * k0v; c21 += p2 * k1v;
    c30 += p3 * k0v; c31 += p3 * k1v;
  }
  ctx[(size_t)(b * 4 + 0) * HID + tid] = c00; ctx[(size_t)(b * 4 + 0) * HID + tid + 256] = c01;
  ctx[(size_t)(b * 4 + 1) * HID + tid] = c10; ctx[(size_t)(b * 4 + 1) * HID + tid + 256] = c11;
  ctx[(size_t)(b * 4 + 2) * HID + tid] = c20; ctx[(size_t)(b * 4 + 2) * HID + tid + 256] = c21;
  ctx[(size_t)(b * 4 + 3) * HID + tid] = c30; ctx[(size_t)(b * 4 + 3) * HID + tid + 256] = c31;
}

// ---------------- sampling: one block per row; JAX partitionable threefry ----------------
__global__ __launch_bounds__(256) void sample_step(
    const float* __restrict__ emb, int t)
{
  __shared__ float rz[256];
  __shared__ int   ri[256];
  __shared__ float rl[256];
  const int row = blockIdx.x;   // 0..511
  const int tid = threadIdx.x;  // 0..255
  const float* logits = g_ws + OFF_LG;
  float* xbuf = g_ws + OFF_X;

  // fold_in(key(42), t): key(42) == (0,42)
  unsigned fk0 = 0u, fk1 = (unsigned)t;
  threefry2x32(0u, 42u, fk0, fk1);

  float l[2], g[2];
#pragma unroll
  for (int j = 0; j < 2; ++j) {
    int v = tid + j * 256;
    unsigned c0 = 0u, c1 = (unsigned)(row * VOC + v);  // 64-bit flat index (hi=0)
    threefry2x32(fk0, fk1, c0, c1);
    g[j] = gumbel_from_bits(c0 ^ c1);                  // partitionable: y0 ^ y1
    l[j] = logits[(size_t)row * VOC + v];
  }

  // phase 1: argmax(logits + gumbel), first-index tie-break
  float z0 = l[0] + g[0], z1 = l[1] + g[1];
  float bz; int bi; float bl;
  if (z1 > z0) { bz = z1; bi = tid + 256; bl = l[1]; }
  else         { bz = z0; bi = tid;       bl = l[0]; }
  rz[tid] = bz; ri[tid] = bi; rl[tid] = bl;
  __syncthreads();
  for (int s = 128; s > 0; s >>= 1) {
    if (tid < s) {
      float oz = rz[tid + s]; int oi = ri[tid + s];
      if (oz > rz[tid] || (oz == rz[tid] && oi < ri[tid])) {
        rz[tid] = oz; ri[tid] = oi; rl[tid] = rl[tid + s];
      }
    }
    __syncthreads();
  }
  const int idx = ri[0];
  const float l_at = rl[0];
  __syncthreads();

  // phase 2: max of logits
  rz[tid] = fmaxf(l[0], l[1]);
  __syncthreads();
  for (int s = 128; s > 0; s >>= 1) {
    if (tid < s) rz[tid] = fmaxf(rz[tid], rz[tid + s]);
    __syncthreads();
  }
  const float m = rz[0];
  __syncthreads();

  // phase 3: S = sum exp(l-m), W = sum exp(l-m)*(l-m)
  float d0 = l[0] - m, d1 = l[1] - m;
  float e0 = expf(d0), e1 = expf(d1);
  rz[tid] = e0 + e1;
  rl[tid] = e0 * d0 + e1 * d1;
  __syncthreads();
  for (int s = 128; s > 0; s >>= 1) {
    if (tid < s) { rz[tid] += rz[tid + s]; rl[tid] += rl[tid + s]; }
    __syncthreads();
  }
  if (tid == 0) {
    float S = rz[0], W = rl[0];
    float logS = logf(S);
    g_ids[t * BN + row] = idx;
    g_ws[OFF_SLP + t * BN + row] = (l_at - m) - logS;   // logp[idx]
    atomicAdd(&g_ws[OFF_ENT + t], logS - W / S);        // row entropy
  }
  // gather next input embedding
  const float* er = emb + (size_t)idx * EMBD;
  xbuf[(size_t)row * EMBD + tid]       = er[tid];
  xbuf[(size_t)row * EMBD + tid + 256] = er[tid + 256];
}

// ---------------- init ----------------
__global__ __launch_bounds__(256) void init_misc(
    const float* __restrict__ y, const float* __restrict__ emb,
    const float* __restrict__ b_ih, const float* __restrict__ b_hh)
{
  int gid = blockIdx.x * 256 + threadIdx.x;  // 0..262143
  int r = gid >> 9, col = gid & 511;
  g_ws[OFF_YR + gid] = y[(size_t)(r >> 2) * HID + col];        // repeat(y, 4, axis=0)
  g_ws[OFF_X + gid]  = emb[(size_t)(VOC - 1) * EMBD + col];    // start token embedding
  if (gid < 2 * NGATE) g_ws[OFF_BG + gid] = b_ih[gid] + b_hh[gid];
  if (gid < 128) g_ws[OFF_ENT + gid] = 0.0f;
}

// ---------------- SINGLE output writer: every element written exactly once (f32) ----------------
__global__ __launch_bounds__(256) void write_out(
    const float* __restrict__ emb, const float* __restrict__ zmask,
    float* __restrict__ out)
{
  long i = (long)blockIdx.x * 256 + threadIdx.x;
  const long stride = (long)gridDim.x * 256;
  for (; i < O_TOTAL; i += stride) {
    float v;
    if (i < O_ZSTATES) {
      // z_ids[b,s,t]: flat = bs*100 + t
      int bs = (int)(i / TLEN), t = (int)(i % TLEN);
      v = (float)g_ids[t * BN + bs];
    } else if (i < O_ZLP) {
      // z_states[b,s,t,e]
      long j = i - O_ZSTATES;
      int e = (int)(j & 511);
      int bst = (int)(j >> 9);
      int bs = bst / TLEN, t = bst % TLEN;
      v = emb[(size_t)g_ids[t * BN + bs] * EMBD + e];
    } else if (i < O_STEP) {
      // z_lp[b,s]
      int bs = (int)(i - O_ZLP);
      int b = bs >> 2;
      float acc = 0.f;
      for (int t = 0; t < TLEN; ++t)
        acc += g_ws[OFF_SLP + t * BN + bs] * zmask[b * TLEN + t];
      v = acc;
    } else if (i < O_ENT) {
      // stepwise[b,s,t]
      long j = i - O_STEP;
      int bs = (int)(j / TLEN), t = (int)(j % TLEN);
      v = g_ws[OFF_SLP + t * BN + bs];
    } else {
      // ent_z scalar
      float e = 0.f;
      for (int t = 0; t < TLEN; ++t) e += g_ws[OFF_ENT + t];
      v = e / (float)(BN * TLEN);
    }
    out[i] = v;
  }
}

// ---------------- host ----------------
extern "C" void kernel_launch(void* const* d_in, const int* in_sizes, int n_in,
                              void* d_out, int out_size, void* d_ws, size_t ws_size,
                              hipStream_t stream) {
  (void)in_sizes; (void)n_in; (void)out_size; (void)d_ws; (void)ws_size;
  const float* y       = (const float*)d_in[0];
  const float* kv      = (const float*)d_in[1];
  const void*  kvm     = (const void*)d_in[2];
  const float* zmask   = (const float*)d_in[3];
  const float* emb     = (const float*)d_in[4];
  const float* W_h0    = (const float*)d_in[5];
  const float* b_h0    = (const float*)d_in[6];
  const float* W_c0    = (const float*)d_in[7];
  const float* b_c0    = (const float*)d_in[8];
  const float* W_ih    = (const float*)d_in[9];
  const float* W_hh    = (const float*)d_in[10];
  const float* b_ih    = (const float*)d_in[11];
  const float* b_hh    = (const float*)d_in[12];
  const float* W_attn  = (const float*)d_in[13];
  const float* W_cproj = (const float*)d_in[14];
  const float* b_cproj = (const float*)d_in[15];
  const float* W_out   = (const float*)d_in[16];
  const float* b_out   = (const float*)d_in[17];
  // d_in[18] = num_sample (==4, hard-coded via NSAMP)
  float* out = (float*)d_out;

  init_misc<<<1024, 256, 0, stream>>>(y, emb, b_ih, b_hh);

  // init h0 / c0: [512,1024] = y_r @ W^T + b   (col block l = layer l state)
  dim3 g_init(1024 / 64, 512 / 64);
  gemm2<<<g_init, 256, 0, stream>>>(OFF_YR, 512, W_h0, 512, 512,
                                    0L, 0, nullptr, 0, 0, b_h0, -1L, OFF_H, 1024);
  gemm2<<<g_init, 256, 0, stream>>>(OFF_YR, 512, W_c0, 512, 512,
                                    0L, 0, nullptr, 0, 0, b_c0, -1L, OFF_C, 1024);

  dim3 g_gates(2048 / 64, 512 / 64);
  dim3 g_sq(512 / 64, 512 / 64);
  const size_t WL = (size_t)NGATE * HID;  // per-layer weight stride

  for (int t = 0; t < TLEN; ++t) {
    // layer 0: gates = x@W_ih0^T + h0@W_hh0^T + (b_ih0+b_hh0)
    gemm2<<<g_gates, 256, 0, stream>>>(OFF_X, 512, W_ih, 512, 512,
                                       OFF_H, 1024, W_hh, 512, 512,
                                       nullptr, OFF_BG, OFF_G, NGATE);
    lstm_cell<<<1024, 256, 0, stream>>>(OFF_H, OFF_C);
    // layer 1: x = new h0 (cols 0..511 of h), h1 at cols 512..1023
    gemm2<<<g_gates, 256, 0, stream>>>(OFF_H, 1024, W_ih + WL, 512, 512,
                                       OFF_H + 512, 1024, W_hh + WL, 512, 512,
                                       nullptr, OFF_BG + NGATE, OFF_G, NGATE);
    lstm_cell<<<1024, 256, 0, stream>>>(OFF_H + 512, OFF_C + 512);
    // q = h1 @ W_attn^T
    gemm2<<<g_sq, 256, 0, stream>>>(OFF_H + 512, 1024, W_attn, 512, 512,
                                    0L, 0, nullptr, 0, 0, nullptr, -1L, OFF_Q, 512);
    attn_kernel<<<128, 256, 0, stream>>>(kv, kvm);
    // out2 = [h1|ctx] @ W_cproj^T + b_cproj
    gemm2<<<g_sq, 256, 0, stream>>>(OFF_H + 512, 1024, W_cproj, 1024, 512,
                                    OFF_CTX, 512, W_cproj + 512, 1024, 512,
                                    b_cproj, -1L, OFF_O2, 512);
    // logits = out2 @ W_out^T + b_out
    gemm2<<<g_sq, 256, 0, stream>>>(OFF_O2, 512, W_out, 512, 512,
                                    0L, 0, nullptr, 0, 0, b_out, -1L, OFF_LG, 512);
    sample_step<<<512, 256, 0, stream>>>(emb, t);
  }

  // single writer for the whole output buffer
  int wblocks = (int)((O_TOTAL + 255L) / 256L);
  write_out<<<wblocks, 256, 0, stream>>>(emb, zmask, out);
}

// Round 5
// 22924.135 us; speedup vs baseline: 1.5812x; 1.5812x over previous
//
#include <hip/hip_runtime.h>
#include <hip/hip_bf16.h>

// Problem constants (fixed by harness inputs)
#define BATCH 128
#define NSAMP 4
#define BN    512        // BATCH*NSAMP
#define HID   512
#define EMBD  512
#define VOC   512
#define TLEN  100
#define MLEN  256
#define NGATE 2048       // 4*HID

#define NPART 8          // split-K partials for all in-loop GEMMs

// output flat offsets (FLOAT32 elements)
#define O_ZID     0L
#define O_ZSTATES 51200L
#define O_ZLP     26265600L
#define O_STEP    26266112L
#define O_ENT     26317312L
#define O_TOTAL   26317313L

// workspace offsets (floats) inside g_ws
#define OFF_H    0L          // [512][1024]
#define OFF_C    524288L     // [512][1024]
#define OFF_X    1048576L    // [512][512]
#define OFF_G    1310720L    // 8 x [512][2048]
#define OFF_Q    9699328L    // 8 x [512][512]
#define OFF_CTX  11796480L   // [512][512]
#define OFF_O2   12058624L   // 8 x [512][512]
#define OFF_LG   14155776L   // 8 x [512][512]
#define OFF_YR   16252928L   // [512][512]
#define OFF_BG   16515072L   // [2][2048]
#define OFF_ENT  16519168L   // [128]
#define OFF_SLP  16519296L   // [100*512]
#define WS_FLOATS 16570496L

#define GPSTRIDE 1048576L    // 512*2048 gate-partial stride
#define SPSTRIDE 262144L     // 512*512 small-partial stride

__device__ float g_ws[WS_FLOATS];
__device__ int   g_ids[TLEN * BN];

// ---------------- threefry2x32 (JAX-exact, 20 rounds) ----------------
__device__ __forceinline__ unsigned rotl32(unsigned x, int r) {
  return (x << r) | (x >> (32 - r));
}
__device__ __forceinline__ void threefry2x32(unsigned k0, unsigned k1,
                                             unsigned& x0, unsigned& x1) {
  unsigned k2 = k0 ^ k1 ^ 0x1BD11BDAu;
#define TF_R(r) { x0 += x1; x1 = rotl32(x1, r); x1 ^= x0; }
  x0 += k0; x1 += k1;
  TF_R(13) TF_R(15) TF_R(26) TF_R(6)
  x0 += k1; x1 += k2 + 1u;
  TF_R(17) TF_R(29) TF_R(16) TF_R(24)
  x0 += k2; x1 += k0 + 2u;
  TF_R(13) TF_R(15) TF_R(26) TF_R(6)
  x0 += k0; x1 += k1 + 3u;
  TF_R(17) TF_R(29) TF_R(16) TF_R(24)
  x0 += k1; x1 += k2 + 4u;
  TF_R(13) TF_R(15) TF_R(26) TF_R(6)
  x0 += k2; x1 += k0 + 5u;
#undef TF_R
}

__device__ __forceinline__ float gumbel_from_bits(unsigned bits) {
  unsigned fb = (bits >> 9) | 0x3F800000u;
  float f = __uint_as_float(fb) - 1.0f;          // [0,1)
  const float TINY = 1.17549435e-38f;
  float u = fmaxf(f + TINY, TINY);
  return -logf(-logf(u));
}

// XLA-style logistic: 0.5 + 0.5*tanh(0.5*x)
__device__ __forceinline__ float sigf(float x) {
  return 0.5f + 0.5f * tanhf(0.5f * x);
}

__device__ __forceinline__ float4 add4(float4 a, float4 b) {
  a.x += b.x; a.y += b.y; a.z += b.z; a.w += b.w; return a;
}

// ---------------- split-K fp32 GEMM: 64 threads, 64x64 tile, 8x8 micro, BK=16 ----------------
// C_partial[kp][m,n] = sum_{k in chunk kp} A[m,k]*B[n,k]  (+bias if kp==0)
// A selected per-chunk from two segments (K1 then K2); A1 may itself be a sum of
// P1 stacked partials (stride strideP1). Kc must divide K1 and 16 | Kc.
__global__ __launch_bounds__(64) void gemmsk(
    long offA1, int lda1, int P1, long strideP1,
    const float* __restrict__ B1, int ldb1, int K1,
    long offA2, int lda2,
    const float* __restrict__ B2, int ldb2,
    const float* __restrict__ biasExt, long biasOff,
    long offC, int ldc, int Kc)
{
  __shared__ float As[16][64];
  __shared__ float Bs[16][64];
  const int t  = threadIdx.x;
  const int tm = t >> 3;         // 0..7
  const int tn = t & 7;          // 0..7
  const int m0 = blockIdx.y * 64;
  const int n0 = blockIdx.x * 64;
  const int kp = blockIdx.z;

  int kbase = kp * Kc;
  const float* A; const float* B; int lda, ldb, P; long strideP;
  if (kbase < K1) {
    A = g_ws + offA1; B = B1; lda = lda1; ldb = ldb1; P = P1; strideP = strideP1;
  } else {
    A = g_ws + offA2; B = B2; lda = lda2; ldb = ldb2; P = 1; strideP = 0;
    kbase -= K1;
  }

  float acc[8][8];
#pragma unroll
  for (int i = 0; i < 8; ++i)
#pragma unroll
    for (int j = 0; j < 8; ++j) acc[i][j] = 0.f;

  for (int k0 = 0; k0 < Kc; k0 += 16) {
    const int kg = kbase + k0;
    // stage A row m0+t, B row n0+t (16 ks each = 4 float4)
    const float* pa = A + (size_t)(m0 + t) * lda + kg;
    float4 a0, a1, a2, a3;
    {
      const float4* q4 = (const float4*)pa;
      a0 = q4[0]; a1 = q4[1]; a2 = q4[2]; a3 = q4[3];
      for (int p = 1; p < P; ++p) {
        const float4* r4 = (const float4*)(pa + (size_t)p * strideP);
        a0 = add4(a0, r4[0]); a1 = add4(a1, r4[1]);
        a2 = add4(a2, r4[2]); a3 = add4(a3, r4[3]);
      }
    }
    const float4* pb = (const float4*)(B + (size_t)(n0 + t) * ldb + kg);
    float4 b0 = pb[0], b1 = pb[1], b2 = pb[2], b3 = pb[3];

    __syncthreads();
    As[ 0][t] = a0.x; As[ 1][t] = a0.y; As[ 2][t] = a0.z; As[ 3][t] = a0.w;
    As[ 4][t] = a1.x; As[ 5][t] = a1.y; As[ 6][t] = a1.z; As[ 7][t] = a1.w;
    As[ 8][t] = a2.x; As[ 9][t] = a2.y; As[10][t] = a2.z; As[11][t] = a2.w;
    As[12][t] = a3.x; As[13][t] = a3.y; As[14][t] = a3.z; As[15][t] = a3.w;
    Bs[ 0][t] = b0.x; Bs[ 1][t] = b0.y; Bs[ 2][t] = b0.z; Bs[ 3][t] = b0.w;
    Bs[ 4][t] = b1.x; Bs[ 5][t] = b1.y; Bs[ 6][t] = b1.z; Bs[ 7][t] = b1.w;
    Bs[ 8][t] = b2.x; Bs[ 9][t] = b2.y; Bs[10][t] = b2.z; Bs[11][t] = b2.w;
    Bs[12][t] = b3.x; Bs[13][t] = b3.y; Bs[14][t] = b3.z; Bs[15][t] = b3.w;
    __syncthreads();

#pragma unroll
    for (int k = 0; k < 16; ++k) {
      float av[8], bv[8];
      *(float4*)&av[0] = *(const float4*)&As[k][tm * 8];
      *(float4*)&av[4] = *(const float4*)&As[k][tm * 8 + 4];
      *(float4*)&bv[0] = *(const float4*)&Bs[k][tn * 8];
      *(float4*)&bv[4] = *(const float4*)&Bs[k][tn * 8 + 4];
#pragma unroll
      for (int i = 0; i < 8; ++i)
#pragma unroll
        for (int j = 0; j < 8; ++j)
          acc[i][j] += av[i] * bv[j];
    }
  }

  const int Mtot = gridDim.y * 64;
  float* C = g_ws + offC + (size_t)kp * (size_t)Mtot * ldc;
  const float* bias = nullptr;
  if (kp == 0)
    bias = biasExt ? biasExt : (biasOff >= 0 ? g_ws + biasOff : nullptr);
#pragma unroll
  for (int i = 0; i < 8; ++i) {
    const int row = m0 + tm * 8 + i;
    const int col = n0 + tn * 8;
    float4 o0, o1;
    o0.x = acc[i][0]; o0.y = acc[i][1]; o0.z = acc[i][2]; o0.w = acc[i][3];
    o1.x = acc[i][4]; o1.y = acc[i][5]; o1.z = acc[i][6]; o1.w = acc[i][7];
    if (bias) {
      o0.x += bias[col];     o0.y += bias[col + 1];
      o0.z += bias[col + 2]; o0.w += bias[col + 3];
      o1.x += bias[col + 4]; o1.y += bias[col + 5];
      o1.z += bias[col + 6]; o1.w += bias[col + 7];
    }
    *(float4*)(C + (size_t)row * ldc + col)     = o0;
    *(float4*)(C + (size_t)row * ldc + col + 4) = o1;
  }
}

// ---------------- old single-pass GEMM (init h0/c0 only) ----------------
__global__ __launch_bounds__(256) void gemm2(
    long offA1, int lda1,
    const float* __restrict__ B1, int ldb1, int K1,
    long offA2, int lda2,
    const float* __restrict__ B2, int ldb2, int K2,
    const float* __restrict__ biasExt, long biasOff,
    long offC, int ldc)
{
  __shared__ float As[16][68];
  __shared__ float Bs[16][68];
  const int tid = threadIdx.x;
  const int tx  = tid & 15;
  const int ty  = tid >> 4;
  const int ldr = tid >> 2;
  const int ldk = (tid & 3) << 2;
  const int m0 = blockIdx.y * 64;
  const int n0 = blockIdx.x * 64;
  float acc[4][4] = {{0.f}};

  for (int seg = 0; seg < 2; ++seg) {
    const float* A = g_ws + (seg ? offA2 : offA1);
    const float* B = seg ? B2 : B1;
    const int lda = seg ? lda2 : lda1;
    const int ldb = seg ? ldb2 : ldb1;
    const int K   = seg ? K2  : K1;
    for (int k0 = 0; k0 < K; k0 += 16) {
      float4 av = *(const float4*)(A + (size_t)(m0 + ldr) * lda + k0 + ldk);
      float4 bv = *(const float4*)(B + (size_t)(n0 + ldr) * ldb + k0 + ldk);
      __syncthreads();
      As[ldk + 0][ldr] = av.x; As[ldk + 1][ldr] = av.y;
      As[ldk + 2][ldr] = av.z; As[ldk + 3][ldr] = av.w;
      Bs[ldk + 0][ldr] = bv.x; Bs[ldk + 1][ldr] = bv.y;
      Bs[ldk + 2][ldr] = bv.z; Bs[ldk + 3][ldr] = bv.w;
      __syncthreads();
#pragma unroll
      for (int k = 0; k < 16; ++k) {
        float4 a = *(const float4*)&As[k][ty * 4];
        float4 b = *(const float4*)&Bs[k][tx * 4];
        acc[0][0] += a.x * b.x; acc[0][1] += a.x * b.y; acc[0][2] += a.x * b.z; acc[0][3] += a.x * b.w;
        acc[1][0] += a.y * b.x; acc[1][1] += a.y * b.y; acc[1][2] += a.y * b.z; acc[1][3] += a.y * b.w;
        acc[2][0] += a.z * b.x; acc[2][1] += a.z * b.y; acc[2][2] += a.z * b.z; acc[2][3] += a.z * b.w;
        acc[3][0] += a.w * b.x; acc[3][1] += a.w * b.y; acc[3][2] += a.w * b.z; acc[3][3] += a.w * b.w;
      }
    }
  }
  const float* bias = biasExt ? biasExt : (biasOff >= 0 ? g_ws + biasOff : nullptr);
  float* C = g_ws + offC;
#pragma unroll
  for (int i = 0; i < 4; ++i) {
    int row = m0 + ty * 4 + i;
    int col = n0 + tx * 4;
    float4 o;
    o.x = acc[i][0]; o.y = acc[i][1]; o.z = acc[i][2]; o.w = acc[i][3];
    if (bias) {
      o.x += bias[col]; o.y += bias[col + 1]; o.z += bias[col + 2]; o.w += bias[col + 3];
    }
    *(float4*)(C + (size_t)row * ldc + col) = o;
  }
}

// ---------------- LSTM cell elementwise; sums NPART gate partials ----------------
__global__ __launch_bounds__(256) void lstm_cell(long hoff, long coff)
{
  int idx = blockIdx.x * 256 + threadIdx.x;   // 0..262143
  int r = idx >> 9, j = idx & 511;
  float gi = 0.f, gf = 0.f, gg = 0.f, go = 0.f;
  const size_t rb = (size_t)r * NGATE;
#pragma unroll
  for (int p = 0; p < NPART; ++p) {
    const float* gr = g_ws + OFF_G + (size_t)p * GPSTRIDE + rb;
    gi += gr[j]; gf += gr[512 + j]; gg += gr[1024 + j]; go += gr[1536 + j];
  }
  float* h = g_ws + hoff;
  float* c = g_ws + coff;
  float cold = c[(size_t)r * 1024 + j];
  float cn = sigf(gf) * cold + sigf(gi) * tanhf(gg);
  float hn = sigf(go) * tanhf(cn);
  c[(size_t)r * 1024 + j] = cn;
  h[(size_t)r * 1024 + j] = hn;
}

// ---------------- attention: block b handles 4 samples sharing kv[b]; sums q partials ----------------
__global__ __launch_bounds__(256) void attn_kernel(
    const float* __restrict__ kv,
    const void*  __restrict__ kvm_raw)
{
  __shared__ float qs[4][512];
  __shared__ float sc[4][256];
  const int b = blockIdx.x;
  const int tid = threadIdx.x;
  const int lane = tid & 63, wave = tid >> 6;
  float* ctx = g_ws + OFF_CTX;
  const float* kvb = kv + (size_t)b * MLEN * HID;
  const unsigned* w32 = (const unsigned*)kvm_raw;
  const unsigned char* u8 = (const unsigned char*)kvm_raw;
  const bool u8mode = (w32[0] == 0x01010101u);
#pragma unroll
  for (int s = 0; s < 4; ++s) {
    float q0 = 0.f, q1 = 0.f;
    const size_t base = (size_t)(b * 4 + s) * HID + tid;
#pragma unroll
    for (int p = 0; p < NPART; ++p) {
      q0 += g_ws[OFF_Q + (size_t)p * SPSTRIDE + base];
      q1 += g_ws[OFF_Q + (size_t)p * SPSTRIDE + base + 256];
    }
    qs[s][tid] = q0; qs[s][tid + 256] = q1;
  }
  __syncthreads();
  // pass 1: scores
  for (int m = wave; m < MLEN; m += 4) {
    const float* kr = kvb + (size_t)m * HID;
    float a0 = 0.f, a1 = 0.f, a2 = 0.f, a3 = 0.f;
    for (int d = lane; d < HID; d += 64) {
      float kvv = kr[d];
      a0 += qs[0][d] * kvv; a1 += qs[1][d] * kvv;
      a2 += qs[2][d] * kvv; a3 += qs[3][d] * kvv;
    }
#pragma unroll
    for (int off = 32; off > 0; off >>= 1) {
      a0 += __shfl_down(a0, off); a1 += __shfl_down(a1, off);
      a2 += __shfl_down(a2, off); a3 += __shfl_down(a3, off);
    }
    if (lane == 0) {
      bool on = u8mode ? (u8[b * MLEN + m] != 0) : (w32[b * MLEN + m] != 0u);
      float madd = on ? 0.0f : -1e9f;
      sc[0][m] = a0 + madd; sc[1][m] = a1 + madd;
      sc[2][m] = a2 + madd; sc[3][m] = a3 + madd;
    }
  }
  __syncthreads();
  // softmax (wave s handles sample s)
  {
    const int s = wave;
    float mx = -3.4e38f;
    for (int m = lane; m < MLEN; m += 64) mx = fmaxf(mx, sc[s][m]);
#pragma unroll
    for (int off = 32; off > 0; off >>= 1) mx = fmaxf(mx, __shfl_xor(mx, off));
    float sum = 0.f;
    for (int m = lane; m < MLEN; m += 64) {
      float e = expf(sc[s][m] - mx);
      sc[s][m] = e; sum += e;
    }
#pragma unroll
    for (int off = 32; off > 0; off >>= 1) sum += __shfl_xor(sum, off);
    for (int m = lane; m < MLEN; m += 64) sc[s][m] = sc[s][m] / sum;
  }
  __syncthreads();
  // pass 2: ctx
  float c00=0,c01=0,c10=0,c11=0,c20=0,c21=0,c30=0,c31=0;
  for (int m = 0; m < MLEN; ++m) {
    float k0v = kvb[(size_t)m * HID + tid];
    float k1v = kvb[(size_t)m * HID + tid + 256];
    float p0 = sc[0][m], p1 = sc[1][m], p2 = sc[2][m], p3 = sc[3][m];
    c00 += p0 * k0v; c01 += p0 * k1v;
    c10 += p1 * k0v; c11 += p1 * k1v;
    c20 += p2 * k0v; c21 += p2 * k1v;
    c30 += p3 * k0v; c31 += p3 * k1v;
  }
  ctx[(size_t)(b * 4 + 0) * HID + tid] = c00; ctx[(size_t)(b * 4 + 0) * HID + tid + 256] = c01;
  ctx[(size_t)(b * 4 + 1) * HID + tid] = c10; ctx[(size_t)(b * 4 + 1) * HID + tid + 256] = c11;
  ctx[(size_t)(b * 4 + 2) * HID + tid] = c20; ctx[(size_t)(b * 4 + 2) * HID + tid + 256] = c21;
  ctx[(size_t)(b * 4 + 3) * HID + tid] = c30; ctx[(size_t)(b * 4 + 3) * HID + tid + 256] = c31;
}

// ---------------- sampling; sums logit partials ----------------
__global__ __launch_bounds__(256) void sample_step(
    const float* __restrict__ emb, int t)
{
  __shared__ float rz[256];
  __shared__ int   ri[256];
  __shared__ float rl[256];
  const int row = blockIdx.x;
  const int tid = threadIdx.x;
  float* xbuf = g_ws + OFF_X;

  unsigned fk0 = 0u, fk1 = (unsigned)t;
  threefry2x32(0u, 42u, fk0, fk1);

  float l[2], g[2];
#pragma unroll
  for (int j = 0; j < 2; ++j) {
    int v = tid + j * 256;
    unsigned c0 = 0u, c1 = (unsigned)(row * VOC + v);
    threefry2x32(fk0, fk1, c0, c1);
    g[j] = gumbel_from_bits(c0 ^ c1);
    float lv = 0.f;
    const size_t base = (size_t)row * VOC + v;
#pragma unroll
    for (int p = 0; p < NPART; ++p)
      lv += g_ws[OFF_LG + (size_t)p * SPSTRIDE + base];
    l[j] = lv;
  }

  float z0 = l[0] + g[0], z1 = l[1] + g[1];
  float bz; int bi; float bl;
  if (z1 > z0) { bz = z1; bi = tid + 256; bl = l[1]; }
  else         { bz = z0; bi = tid;       bl = l[0]; }
  rz[tid] = bz; ri[tid] = bi; rl[tid] = bl;
  __syncthreads();
  for (int s = 128; s > 0; s >>= 1) {
    if (tid < s) {
      float oz = rz[tid + s]; int oi = ri[tid + s];
      if (oz > rz[tid] || (oz == rz[tid] && oi < ri[tid])) {
        rz[tid] = oz; ri[tid] = oi; rl[tid] = rl[tid + s];
      }
    }
    __syncthreads();
  }
  const int idx = ri[0];
  const float l_at = rl[0];
  __syncthreads();

  rz[tid] = fmaxf(l[0], l[1]);
  __syncthreads();
  for (int s = 128; s > 0; s >>= 1) {
    if (tid < s) rz[tid] = fmaxf(rz[tid], rz[tid + s]);
    __syncthreads();
  }
  const float m = rz[0];
  __syncthreads();

  float d0 = l[0] - m, d1 = l[1] - m;
  float e0 = expf(d0), e1 = expf(d1);
  rz[tid] = e0 + e1;
  rl[tid] = e0 * d0 + e1 * d1;
  __syncthreads();
  for (int s = 128; s > 0; s >>= 1) {
    if (tid < s) { rz[tid] += rz[tid + s]; rl[tid] += rl[tid + s]; }
    __syncthreads();
  }
  if (tid == 0) {
    float S = rz[0], W = rl[0];
    float logS = logf(S);
    g_ids[t * BN + row] = idx;
    g_ws[OFF_SLP + t * BN + row] = (l_at - m) - logS;
    atomicAdd(&g_ws[OFF_ENT + t], logS - W / S);
  }
  const float* er = emb + (size_t)idx * EMBD;
  xbuf[(size_t)row * EMBD + tid]       = er[tid];
  xbuf[(size_t)row * EMBD + tid + 256] = er[tid + 256];
}

// ---------------- init ----------------
__global__ __launch_bounds__(256) void init_misc(
    const float* __restrict__ y, const float* __restrict__ emb,
    const float* __restrict__ b_ih, const float* __restrict__ b_hh)
{
  int gid = blockIdx.x * 256 + threadIdx.x;
  int r = gid >> 9, col = gid & 511;
  g_ws[OFF_YR + gid] = y[(size_t)(r >> 2) * HID + col];
  g_ws[OFF_X + gid]  = emb[(size_t)(VOC - 1) * EMBD + col];
  if (gid < 2 * NGATE) g_ws[OFF_BG + gid] = b_ih[gid] + b_hh[gid];
  if (gid < 128) g_ws[OFF_ENT + gid] = 0.0f;
}

// ---------------- SINGLE output writer (f32) ----------------
__global__ __launch_bounds__(256) void write_out(
    const float* __restrict__ emb, const float* __restrict__ zmask,
    float* __restrict__ out)
{
  long i = (long)blockIdx.x * 256 + threadIdx.x;
  const long stride = (long)gridDim.x * 256;
  for (; i < O_TOTAL; i += stride) {
    float v;
    if (i < O_ZSTATES) {
      int bs = (int)(i / TLEN), t = (int)(i % TLEN);
      v = (float)g_ids[t * BN + bs];
    } else if (i < O_ZLP) {
      long j = i - O_ZSTATES;
      int e = (int)(j & 511);
      int bst = (int)(j >> 9);
      int bs = bst / TLEN, t = bst % TLEN;
      v = emb[(size_t)g_ids[t * BN + bs] * EMBD + e];
    } else if (i < O_STEP) {
      int bs = (int)(i - O_ZLP);
      int b = bs >> 2;
      float acc = 0.f;
      for (int t = 0; t < TLEN; ++t)
        acc += g_ws[OFF_SLP + t * BN + bs] * zmask[b * TLEN + t];
      v = acc;
    } else if (i < O_ENT) {
      long j = i - O_STEP;
      int bs = (int)(j / TLEN), t = (int)(j % TLEN);
      v = g_ws[OFF_SLP + t * BN + bs];
    } else {
      float e = 0.f;
      for (int t = 0; t < TLEN; ++t) e += g_ws[OFF_ENT + t];
      v = e / (float)(BN * TLEN);
    }
    out[i] = v;
  }
}

// ---------------- host ----------------
extern "C" void kernel_launch(void* const* d_in, const int* in_sizes, int n_in,
                              void* d_out, int out_size, void* d_ws, size_t ws_size,
                              hipStream_t stream) {
  (void)in_sizes; (void)n_in; (void)out_size; (void)d_ws; (void)ws_size;
  const float* y       = (const float*)d_in[0];
  const float* kv      = (const float*)d_in[1];
  const void*  kvm     = (const void*)d_in[2];
  const float* zmask   = (const float*)d_in[3];
  const float* emb     = (const float*)d_in[4];
  const float* W_h0    = (const float*)d_in[5];
  const float* b_h0    = (const float*)d_in[6];
  const float* W_c0    = (const float*)d_in[7];
  const float* b_c0    = (const float*)d_in[8];
  const float* W_ih    = (const float*)d_in[9];
  const float* W_hh    = (const float*)d_in[10];
  const float* b_ih    = (const float*)d_in[11];
  const float* b_hh    = (const float*)d_in[12];
  const float* W_attn  = (const float*)d_in[13];
  const float* W_cproj = (const float*)d_in[14];
  const float* b_cproj = (const float*)d_in[15];
  const float* W_out   = (const float*)d_in[16];
  const float* b_out   = (const float*)d_in[17];
  float* out = (float*)d_out;

  init_misc<<<1024, 256, 0, stream>>>(y, emb, b_ih, b_hh);

  // init h0 / c0 (outside loop, old kernel)
  dim3 g_init(1024 / 64, 512 / 64);
  gemm2<<<g_init, 256, 0, stream>>>(OFF_YR, 512, W_h0, 512, 512,
                                    0L, 0, nullptr, 0, 0, b_h0, -1L, OFF_H, 1024);
  gemm2<<<g_init, 256, 0, stream>>>(OFF_YR, 512, W_c0, 512, 512,
                                    0L, 0, nullptr, 0, 0, b_c0, -1L, OFF_C, 1024);

  dim3 g_gates(2048 / 64, 512 / 64, NPART);   // Kc=128 over K=1024
  dim3 g_sq(512 / 64, 512 / 64, NPART);
  const size_t WL = (size_t)NGATE * HID;

  for (int t = 0; t < TLEN; ++t) {
    // layer 0 gates
    gemmsk<<<g_gates, 64, 0, stream>>>(OFF_X, 512, 1, 0L, W_ih, 512, 512,
                                       OFF_H, 1024, W_hh, 512,
                                       nullptr, OFF_BG, OFF_G, NGATE, 128);
    lstm_cell<<<1024, 256, 0, stream>>>(OFF_H, OFF_C);
    // layer 1 gates
    gemmsk<<<g_gates, 64, 0, stream>>>(OFF_H, 1024, 1, 0L, W_ih + WL, 512, 512,
                                       OFF_H + 512, 1024, W_hh + WL, 512,
                                       nullptr, OFF_BG + NGATE, OFF_G, NGATE, 128);
    lstm_cell<<<1024, 256, 0, stream>>>(OFF_H + 512, OFF_C + 512);
    // q = h1 @ W_attn^T   (Kc=64 over K=512)
    gemmsk<<<g_sq, 64, 0, stream>>>(OFF_H + 512, 1024, 1, 0L, W_attn, 512, 512,
                                    0L, 0, nullptr, 0,
                                    nullptr, -1L, OFF_Q, 512, 64);
    attn_kernel<<<128, 256, 0, stream>>>(kv, kvm);
    // out2 = [h1|ctx] @ W_cproj^T + b  (Kc=128 over K=1024)
    gemmsk<<<g_sq, 64, 0, stream>>>(OFF_H + 512, 1024, 1, 0L, W_cproj, 1024, 512,
                                    OFF_CTX, 512, W_cproj + 512, 1024,
                                    b_cproj, -1L, OFF_O2, 512, 128);
    // logits = out2 @ W_out^T + b  (A sums 8 out2 partials; Kc=64)
    gemmsk<<<g_sq, 64, 0, stream>>>(OFF_O2, 512, NPART, SPSTRIDE, W_out, 512, 512,
                                    0L, 0, nullptr, 0,
                                    b_out, -1L, OFF_LG, 512, 64);
    sample_step<<<512, 256, 0, stream>>>(emb, t);
  }

  int wblocks = (int)((O_TOTAL + 255L) / 256L);
  write_out<<<wblocks, 256, 0, stream>>>(emb, zmask, out);
}